// Round 10
// baseline (188.579 us; speedup 1.0000x reference)
//
#include <hip/hip_runtime.h>

// Bit-exact emulation of segmented sparsemax with cumsum lowered like XLA's
// ReduceWindowRewriter (base 16). GREEN since R7 (absmax 0.0).
// R24 (179.9us): float4 S-store NEUTRAL-NEG (bank conflicts 0.65M->1.0M),
//   kCF/kB vec neutral -> remainder (~116us) is structural: k1_bounds' full
//   33.5MB pass + 4 launch gaps + small-kernel latency, not access width.
// R25:
//   - k1_bounds ELIMINATED: each k2w wave binary-searches batch for
//     [LB(b), LB(b+1)) (two interleaved 23-step searches, wave-uniform ->
//     scalar loads) and writes starts[b] (+starts[NSEG] by the last wave)
//     for kM1/kCF. Deletes a 33.5MB HBM pass + one launch gap.
//   - k2w S-store back to scalar (R23 measured-best; undoes conflict rise).
//   - kB/kCF keep R24 float4 forms.
// All scan arithmetic keeps the exact association order of the verified chain.

#define NSEG   8192
#define NTOT   8388608   // 2^23
#define L1N    524288    // 2^19
#define L2N    32768     // 2^15
#define L3N    2048
#define PADV   (-3.0e38f)
#define WREG   1216      // per-wave LDS floats (capacity 1024 + 192)
#define FBB    256

__device__ __forceinline__ int esw(const int e) {
    return (e & ~15) | ((e + (e >> 4)) & 15);
}

// xor-shuffle: DPP for tm=1,2,8 (VALU pipe); ds path otherwise.
// tm must be a compile-time constant at each (unrolled) call site.
__device__ __forceinline__ float sxor(const float v, const int tm) {
    if (tm == 1)
        return __int_as_float(__builtin_amdgcn_mov_dpp(__float_as_int(v), 0xB1, 0xF, 0xF, true));
    if (tm == 2)
        return __int_as_float(__builtin_amdgcn_mov_dpp(__float_as_int(v), 0x4E, 0xF, 0xF, true));
    if (tm == 8)
        return __int_as_float(__builtin_amdgcn_mov_dpp(__float_as_int(v), 0x128, 0xF, 0xF, true));
    return __shfl_xor(v, tm, 64);
}

// compile-time-direction comparator (prologue): min/max, 2 ops
__device__ __forceinline__ void cs(float& a, float& b, const bool up) {
    const float lo = fminf(a, b), hi = fmaxf(a, b);
    a = up ? hi : lo;
    b = up ? lo : hi;
}
// runtime-direction comparator: cmp + 2 cndmask (equal values keep bits: no -0/NaN)
__device__ __forceinline__ void csr(float& a, float& b, const bool up) {
    const bool sw = ((a > b) != up);
    const float t = a;
    a = sw ? b : a;
    b = sw ? t : b;
}

// ---- 4-reg (256) overflow sort ----
__device__ __forceinline__ void sort4(float r[4], const int gib) {
    cs(r[0], r[1], true);  cs(r[2], r[3], false);
    const bool u4 = ((gib & 4) == 0);
    cs(r[0], r[2], u4); cs(r[1], r[3], u4);
    cs(r[0], r[1], u4); cs(r[2], r[3], u4);
}

template<int K>
__device__ __forceinline__ void bmerge4(float r[4], const int gib) {
    const bool up = ((gib & K) == 0);
    #pragma unroll
    for (int j = K >> 1; j >= 4; j >>= 1) {
        const bool tkm = (up == ((gib & j) == 0));
        const int tm = j >> 2;
        #pragma unroll
        for (int m = 0; m < 4; ++m) {
            const float p = sxor(r[m], tm);
            r[m] = ((r[m] > p) == tkm) ? r[m] : p;
        }
    }
    #pragma unroll
    for (int j = 2; j >= 1; j >>= 1)
        #pragma unroll
        for (int m = 0; m < 4; ++m)
            if ((m & j) == 0) csr(r[m], r[m | j], up);
}

// ---- 16-reg (1024) wave sort (verified network since R9; R23 comparators) ----
template<int K, int J>
__device__ __forceinline__ void cepm(float r[16]) {
    #pragma unroll
    for (int m = 0; m < 16; ++m)
        if ((m & J) == 0) { const bool up = ((m & K) == 0); cs(r[m], r[m | J], up); }
}
template<int J>
__device__ __forceinline__ void cep(float r[16], const bool up) {
    #pragma unroll
    for (int m = 0; m < 16; ++m)
        if ((m & J) == 0) cs(r[m], r[m | J], up);
}
template<int KD>
__device__ __forceinline__ void kphase16(float r[16], const int l) {
    const bool up = ((l & (KD >> 4)) == 0);   // KD=1024: folds to true (l<64)
    #pragma unroll
    for (int tm = KD >> 5; tm >= 1; tm >>= 1) {
        const bool tkm = (up == ((l & tm) == 0));
        #pragma unroll
        for (int m = 0; m < 16; ++m) {
            const float p = sxor(r[m], tm);
            r[m] = ((r[m] > p) == tkm) ? r[m] : p;
        }
    }
    if (KD >= 1024) {
        cep<8>(r, up); cep<4>(r, up); cep<2>(r, up); cep<1>(r, up);   // up const
    } else {
        #pragma unroll
        for (int j = 8; j >= 1; j >>= 1)
            #pragma unroll
            for (int m = 0; m < 16; ++m)
                if ((m & j) == 0) csr(r[m], r[m | j], up);
    }
}
__device__ __forceinline__ void wsort1024(float r[16], const int l) {
    cepm<2, 1>(r);
    cepm<4, 2>(r); cepm<4, 1>(r);
    cepm<8, 4>(r); cepm<8, 2>(r); cepm<8, 1>(r);
    kphase16<16>(r, l);  kphase16<32>(r, l);  kphase16<64>(r, l);
    kphase16<128>(r, l); kphase16<256>(r, l); kphase16<512>(r, l);
    kphase16<1024>(r, l);
}

// -------- k2w: one WAVE per segment (R25: self-bounds + writes starts) --------
__global__ __launch_bounds__(256) void k2w(
    const float* __restrict__ x, const int* __restrict__ batch,
    int* __restrict__ starts, float* __restrict__ mx_out,
    float* __restrict__ S, float* __restrict__ L1)
{
    __shared__ __align__(16) float Wall[4 * WREG];   // 19456 B
    const int tid  = threadIdx.x;
    const int lane = tid & 63;
    const int wid  = tid >> 6;
    float* W = Wall + wid * WREG;

    const int b = blockIdx.x * 4 + wid;

    // bounds via two interleaved binary searches (LB(b), LB(b+1)); wave-uniform
    int lo0 = 0, hi0 = NTOT, lo1 = 0, hi1 = NTOT;
    #pragma unroll 1
    for (int it = 0; it < 23; ++it) {
        if (lo0 < hi0) { const int m = (lo0 + hi0) >> 1; if (batch[m] < b) lo0 = m + 1; else hi0 = m; }
        if (lo1 < hi1) { const int m = (lo1 + hi1) >> 1; if (batch[m] < b + 1) lo1 = m + 1; else hi1 = m; }
    }
    const int s = lo0, e = lo1;
    if (lane == 0) {
        starts[b] = s;
        if (b == NSEG - 1) starts[NSEG] = NTOT;
    }
    const int n = e - s;
    if (n <= 0) { if (lane == 0) mx_out[b] = 0.0f; return; }

    const bool med = (n > 1024);
    const int  nb  = n - 1024;                      // <= 192 by capacity (mean+6sigma)

    float r[16], rb[4];
    // coalesced: element (64*m + lane); any permutation sorts to the same S
    #pragma unroll
    for (int m = 0; m < 16; ++m) { const int i = (m << 6) + lane; r[m] = (i < n) ? x[s + i] : PADV; }
    if (med) {
        #pragma unroll
        for (int m = 0; m < 4; ++m) { const int i = 1024 + (m << 6) + lane; rb[m] = (i < n) ? x[s + i] : PADV; }
    }

    float mx = r[0];
    #pragma unroll
    for (int m = 1; m < 16; ++m) mx = fmaxf(mx, r[m]);
    if (med) {
        #pragma unroll
        for (int m = 0; m < 4; ++m) mx = fmaxf(mx, rb[m]);
    }
    #pragma unroll
    for (int o = 32; o; o >>= 1) mx = fmaxf(mx, sxor(mx, o));
    if (lane == 0) mx_out[b] = mx;

    #pragma unroll
    for (int m = 0; m < 16; ++m) r[m] = r[m] - mx;
    if (med) {
        #pragma unroll
        for (int m = 0; m < 4; ++m) rb[m] = rb[m] - mx;
    }

    wsort1024(r, lane);

    if (med) {
        const int gib = 4 * lane;
        sort4(rb, gib);
        bmerge4<8>(rb, gib);   bmerge4<16>(rb, gib);  bmerge4<32>(rb, gib);
        bmerge4<64>(rb, gib);  bmerge4<128>(rb, gib); bmerge4<256>(rb, gib);
        // rb = V[k] desc over k = 4*lane + j (PADV tail for k >= nb)

        // ---- register bitonic merge of M(1024, desc, r[]) with V(256, desc, rb[]) ----
        // half-cleaner, distance 1024: real partners only for lanes 48..63:
        // partner of g=16*lane+m is V[k], k = 16*(63-lane)+(15-m).
        float tu[16];
        #pragma unroll
        for (int m = 0; m < 16; ++m) {
            const int k  = ((63 - lane) << 4) + (15 - m);
            const int sk = (k >> 2) & 63;               // V[k] lives at lane k>>2, reg k&3
            const float pv = __shfl(rb[(15 - m) & 3], sk, 64);
            const float hi = fmaxf(r[m], pv);
            const float lo = fminf(r[m], pv);
            const bool act = (lane >= 48);
            tu[m] = act ? lo : PADV;                    // upper half (ranks 1024+)
            r[m]  = act ? hi : r[m];                    // lower half keeps max
        }
        // lower half: desc merge of a bitonic 1024 == the verified kphase16<1024>
        kphase16<1024>(r, lane);
        // upper half: 256 survivors U[t], t = 16*(lane-48)+m: desc 256-merge.
        #pragma unroll
        for (int tm = 8; tm >= 1; tm >>= 1) {
            const bool tkm = ((lane & tm) == 0);
            #pragma unroll
            for (int m = 0; m < 16; ++m) {
                const float p = sxor(tu[m], tm);
                tu[m] = ((tu[m] > p) == tkm) ? tu[m] : p;
            }
        }
        cep<8>(tu, true); cep<4>(tu, true); cep<2>(tu, true); cep<1>(tu, true);

        #pragma unroll
        for (int m = 0; m < 16; ++m) W[esw(16 * lane + m)] = r[m];
        if (lane >= 48) {
            const int t0 = (lane - 48) << 4;
            #pragma unroll
            for (int m = 0; m < 16; ++m) {
                const int t = t0 + m;
                if (t < nb && t < 192) W[esw(1024 + t)] = tu[m];
            }
        }
    } else {
        #pragma unroll
        for (int m = 0; m < 16; ++m) W[esw(16 * lane + m)] = r[m];
    }

    for (int i = lane; i < n; i += 64) S[s + i] = W[esw(i)];

    const int q0 = (s + 15) >> 4, q1 = e >> 4;
    for (int rr = lane; rr < q1 - q0; rr += 64) {
        const int lb = ((q0 + rr) << 4) - s;
        float v[16];
        #pragma unroll
        for (int ii = 0; ii < 16; ++ii) v[ii] = W[esw(lb + ii)];
        float a = 0.0f;
        #pragma unroll
        for (int ii = 0; ii < 16; ++ii) a = a + v[ii];
        L1[q0 + rr] = a;
    }
}

// -------- kM1: border-row fix + L1 -> L2 -> L3 (128 blocks, no cross-block dep) --------
__global__ __launch_bounds__(256) void kM1(
    const float* __restrict__ S, const int* __restrict__ starts,
    float* __restrict__ L1, float* __restrict__ L2, float* __restrict__ L3)
{
    __shared__ float l2s[256];
    __shared__ int sbr[2];
    const int k = blockIdx.x, tid = threadIdx.x;

    // segments with starts in [65536k, 65536(k+1)) have border rows in this
    // block's L1 window [4096k, 4096(k+1))
    if (tid < 2) {
        const int target = 65536 * (k + tid);
        int lo = 0, hi = NSEG;
        while (lo < hi) { const int mid = (lo + hi) >> 1; if (starts[mid] < target) lo = mid + 1; else hi = mid; }
        sbr[tid] = lo;
    }
    __syncthreads();
    for (int b = sbr[0] + tid; b < sbr[1]; b += 256) {
        const int s = starts[b];
        if (s & 15) {
            const int q = s >> 4;
            const float* p = S + ((size_t)q << 4);
            float a = 0.0f;
            #pragma unroll
            for (int i = 0; i < 16; ++i) a = a + p[i];
            L1[q] = a;
        }
    }
    __syncthreads();   // border rows visible to this block's reads below

    const int q2 = (k << 8) + tid;
    {
        const float* p = L1 + ((size_t)q2 << 4);
        float a = 0.0f;
        #pragma unroll
        for (int i = 0; i < 16; ++i) a = a + p[i];   // rows may mix scalar/vec writes; scalar reads safe
        L2[q2] = a;
        l2s[tid] = a;
    }
    __syncthreads();
    if (tid < 16) {
        float a = 0.0f;
        #pragma unroll
        for (int i = 0; i < 16; ++i) a = a + l2s[(tid << 4) + i];
        L3[(k << 4) + tid] = a;
    }
}

// -------- kB: redundant in-LDS pyramid (L3->C3), C2 slice, C1 chunk (R24 f4 chunk) --------
__global__ __launch_bounds__(256) void kB(const float* __restrict__ L1,
                                          const float* __restrict__ L2,
                                          const float* __restrict__ L3g,
                                          float* __restrict__ C1)
{
    __shared__ float l3[L3N], c3[L3N], l4[128], c4[128], l5[8], c5[8], c2s[256];
    const int k = blockIdx.x, tid = threadIdx.x;

    for (int q = tid; q < L3N; q += 256) l3[q] = L3g[q];
    __syncthreads();
    if (tid < 128) {
        float a = 0.0f;
        for (int i = 0; i < 16; ++i) a = a + l3[tid * 16 + i];
        l4[tid] = a;
    }
    __syncthreads();
    if (tid < 8) {
        float a = 0.0f;
        for (int i = 0; i < 16; ++i) a = a + l4[tid * 16 + i];
        l5[tid] = a;
    }
    __syncthreads();
    if (tid == 0) {
        float a = 0.0f;
        for (int i = 0; i < 8; ++i) { a = a + l5[i]; c5[i] = a; }
    }
    __syncthreads();
    if (tid < 8) {
        const float pre = tid ? c5[tid - 1] : 0.0f;
        float a = 0.0f;
        for (int i = 0; i < 16; ++i) { a = a + l4[tid * 16 + i]; c4[tid * 16 + i] = tid ? (a + pre) : a; }
    }
    __syncthreads();
    if (tid < 128) {
        const float pre = tid ? c4[tid - 1] : 0.0f;
        float a = 0.0f;
        for (int i = 0; i < 16; ++i) { a = a + l3[tid * 16 + i]; c3[tid * 16 + i] = tid ? (a + pre) : a; }
    }
    __syncthreads();
    if (tid < 16) {
        const int q2r = (k << 4) + tid;
        const float pre = q2r ? c3[q2r - 1] : 0.0f;
        const float* p = L2 + ((size_t)q2r << 4);
        float a = 0.0f;
        #pragma unroll
        for (int i = 0; i < 16; ++i) { a = a + p[i]; c2s[(tid << 4) + i] = q2r ? (a + pre) : a; }
    }
    __syncthreads();
    {
        const int p1 = (k << 8) + 1 + tid;
        if (p1 < L2N) {
            const float pre = c2s[tid];
            const float4* pL4 = (const float4*)(L1 + ((size_t)p1 << 4));
            float o[16];
            float a = 0.0f;
            #pragma unroll
            for (int v = 0; v < 4; ++v) {
                const float4 f = pL4[v];
                a = a + f.x; o[4 * v + 0] = a + pre;
                a = a + f.y; o[4 * v + 1] = a + pre;
                a = a + f.z; o[4 * v + 2] = a + pre;
                a = a + f.w; o[4 * v + 3] = a + pre;
            }
            float4* c4p = (float4*)(C1 + ((size_t)p1 << 4));
            #pragma unroll
            for (int v = 0; v < 4; ++v) {
                float4 f;
                f.x = o[4 * v + 0]; f.y = o[4 * v + 1];
                f.z = o[4 * v + 2]; f.w = o[4 * v + 3];
                c4p[v] = f;
            }
        }
        if (k == 0 && tid == 0) {
            float a = 0.0f;
            #pragma unroll
            for (int i = 0; i < 16; ++i) { a = a + L1[i]; C1[i] = a; }
        }
    }
}

// c(j) helper: full-row fold + C1 prefix (exact chain)
__device__ __forceinline__ float c_row(const int j, const float* __restrict__ S,
                                       const float* __restrict__ C1)
{
    const int q = j >> 4;
    const float* p = S + ((size_t)q << 4);
    float a = 0.0f;
    for (int i = 0; i <= (j & 15); ++i) a = a + p[i];
    return q ? (a + C1[q - 1]) : a;
}

// -------- kCF (big-ws): 4 segs/block, one wave each — R24 float4 epilogue --------
__global__ __launch_bounds__(256) void kCF(
    const float* __restrict__ x, const float* __restrict__ S, const float* __restrict__ C1,
    const int* __restrict__ starts, const int* __restrict__ batch,
    const float* __restrict__ mx, float* __restrict__ out)
{
    const int lane = threadIdx.x & 63;
    const int b = blockIdx.x * 4 + (threadIdx.x >> 6);
    const int s = starts[b], e = starts[b + 1];
    const int n = e - s;
    if (n <= 0) return;

    float base = 0.0f;
    if (lane == 0 && s > 0) base = c_row(s - 1, S, C1);
    base = __shfl(base, 0, 64);

    const int q0 = s >> 4;
    const int nrows = ((e - 1) >> 4) - q0 + 1;
    const int R = (nrows < 32) ? nrows : 32;   // exact-margin cap (R12-verified)

    int cnt = 0;
    for (int rr = lane; rr < R; rr += 64) {
        const int q = q0 + rr;
        const float pre = q ? C1[q - 1] : 0.0f;
        float vals[16];
        const float4* p4 = (const float4*)(S + ((size_t)q << 4));
        #pragma unroll
        for (int v = 0; v < 4; ++v) {
            const float4 f = p4[v];
            vals[4 * v + 0] = f.x; vals[4 * v + 1] = f.y;
            vals[4 * v + 2] = f.z; vals[4 * v + 3] = f.w;
        }
        float a = 0.0f;
        #pragma unroll
        for (int i = 0; i < 16; ++i) {
            a = a + vals[i];                         // full-row fold (bit-exact)
            const int j = (q << 4) + i;
            if (j >= s && j < e) {
                const float cj  = q ? (a + pre) : a;
                const float seg = (cj - base) - 1.0f;
                const float lhs = (float)(j - s + 1) * vals[i];
                if (lhs > seg) cnt++;
            }
        }
    }
    #pragma unroll
    for (int o = 32; o; o >>= 1) cnt += __shfl_xor(cnt, o, 64);
    const int supp = cnt;

    float t = 0.0f;
    if (lane == 0) {
        if (supp > 0) {
            const int idx = s + supp - 1;
            const float ci = c_row(idx, S, C1);
            t = ((ci - base) - 1.0f) / (float)supp;
        } else {
            const int g  = batch[s - 1];             // leak: prev segment (s>0 here)
            const int sg = starts[g];
            const float bg = (sg > 0) ? c_row(sg - 1, S, C1) : 0.0f;
            t = (base - bg) - 1.0f;
        }
    }
    t = __shfl(t, 0, 64);
    const float tb = t;
    const float mxb = mx[b];

    // epilogue: aligned head / float4 body / tail (elementwise, bit-exact)
    const int sA = (s + 3) & ~3;
    const int eA = e & ~3;
    if (sA >= eA) {
        for (int i = s + lane; i < e; i += 64) {
            float v = x[i] - mxb;
            v = v - tb;
            out[i] = v > 0.0f ? v : 0.0f;
        }
    } else {
        if (lane < sA - s) {
            const int i = s + lane;
            float v = x[i] - mxb;
            v = v - tb;
            out[i] = v > 0.0f ? v : 0.0f;
        }
        for (int c = sA + (lane << 2); c < eA; c += 256) {
            float4 f = *(const float4*)(x + c);
            f.x = f.x - mxb; f.x = f.x - tb; f.x = f.x > 0.0f ? f.x : 0.0f;
            f.y = f.y - mxb; f.y = f.y - tb; f.y = f.y > 0.0f ? f.y : 0.0f;
            f.z = f.z - mxb; f.z = f.z - tb; f.z = f.z > 0.0f ? f.z : 0.0f;
            f.w = f.w - mxb; f.w = f.w - tb; f.w = f.w > 0.0f ? f.w : 0.0f;
            *(float4*)(out + c) = f;
        }
        if (lane < e - eA) {
            const int i = eA + lane;
            float v = x[i] - mxb;
            v = v - tb;
            out[i] = v > 0.0f ? v : 0.0f;
        }
    }
}

// -------- small-ws fallback pair: k_base + kC (R13-verified, S aliased with out) --------
__global__ void k_base(const float* __restrict__ S, const float* __restrict__ C1,
                       const int* __restrict__ starts,
                       float* __restrict__ baseA, float* __restrict__ rowP)
{
    const int b = blockIdx.x * blockDim.x + threadIdx.x;
    if (b >= NSEG) return;
    const int s = starts[b];
    float P = 0.0f, base = 0.0f;
    if (s > 0) {
        const int j = s - 1;
        const int q = j >> 4;
        const float* p = S + ((size_t)q << 4);
        float a = 0.0f;
        for (int i = 0; i <= (j & 15); ++i) a = a + p[i];
        if (s & 15) P = a;
        base = q ? (a + C1[q - 1]) : a;
    }
    baseA[b] = base;
    rowP[b] = P;
}

__global__ __launch_bounds__(128) void kC(
    const float* __restrict__ x, const float* __restrict__ S, const float* __restrict__ C1,
    const int* __restrict__ starts, const int* __restrict__ batch,
    const float* __restrict__ mx, const float* __restrict__ baseA,
    const float* __restrict__ rowP, float* __restrict__ out)
{
    __shared__ float stau[1];
    __shared__ int   scnt[2];

    const int b = blockIdx.x, tid = threadIdx.x;
    const int s = starts[b], e = starts[b + 1];
    const int n = e - s;
    if (n <= 0) return;

    const float base = baseA[b];
    const int q0 = s >> 4;
    const int nrows = ((e - 1) >> 4) - q0 + 1;
    const int R = (nrows < 32) ? nrows : 32;

    int cnt = 0;
    for (int rr = tid; rr < R; rr += 128) {
        const int q = q0 + rr;
        const float pre = q ? C1[q - 1] : 0.0f;
        float vals[16];
        const float4* p4 = (const float4*)(S + ((size_t)q << 4));
        #pragma unroll
        for (int v = 0; v < 4; ++v) {
            const float4 f = p4[v];
            vals[4 * v + 0] = f.x; vals[4 * v + 1] = f.y;
            vals[4 * v + 2] = f.z; vals[4 * v + 3] = f.w;
        }
        float a = (rr == 0) ? rowP[b] : 0.0f;
        const int i0 = (rr == 0) ? (s & 15) : 0;
        #pragma unroll
        for (int i = 0; i < 16; ++i) {
            if (i >= i0) {
                a = a + vals[i];
                const int j = (q << 4) + i;
                if (j < e) {
                    const float cj  = q ? (a + pre) : a;
                    const float seg = (cj - base) - 1.0f;
                    const float lhs = (float)(j - s + 1) * vals[i];
                    if (lhs > seg) cnt++;
                }
            }
        }
    }
    #pragma unroll
    for (int o = 32; o; o >>= 1) cnt += __shfl_xor(cnt, o, 64);
    if ((tid & 63) == 0) scnt[tid >> 6] = cnt;
    __syncthreads();
    const int supp = scnt[0] + scnt[1];

    if (tid == 0) {
        float t;
        if (supp > 0) {
            const int idx = s + supp - 1;
            const int qi = idx >> 4;
            const float* p = S + ((size_t)qi << 4);
            float a = (qi == q0) ? rowP[b] : 0.0f;
            const int i0 = (qi == q0) ? (s & 15) : 0;
            for (int i = i0; i <= (idx & 15); ++i) a = a + p[i];
            const float ci = qi ? (a + C1[qi - 1]) : a;
            t = ((ci - base) - 1.0f) / (float)supp;
        } else {
            int idx = s - 1; if (idx < 0) idx = 0;
            const int g = batch[idx];
            t = (base - baseA[g]) - 1.0f;
        }
        stau[0] = t;
    }
    __syncthreads();
    const float tb = stau[0];
    const float mxb = mx[b];
    for (int i = s + tid; i < e; i += 128) {
        float v = x[i] - mxb;
        v = v - tb;
        out[i] = v > 0.0f ? v : 0.0f;
    }
}

// ---------------- fallback (shape mismatch): plain sparsemax + sentinel ----------------
__global__ void fb_sparsemax(const float* x, const int* batch, float* out, int n_total)
{
    __shared__ float sred[FBB];
    __shared__ int   sredi[FBB];
    __shared__ int   sb2[2];
    const int tid = threadIdx.x;
    const int b = blockIdx.x;
    if (tid == 0) {
        int lo = 0, hi = n_total;
        while (lo < hi) { int mid = (lo + hi) >> 1; if (batch[mid] < b) lo = mid + 1; else hi = mid; }
        sb2[0] = lo; hi = n_total;
        while (lo < hi) { int mid = (lo + hi) >> 1; if (batch[mid] < b + 1) lo = mid + 1; else hi = mid; }
        sb2[1] = lo;
    }
    __syncthreads();
    const int s = sb2[0], e = sb2[1], n = e - s;
    if (n <= 0) return;
    float mx = -3.0e38f;
    for (int i = s + tid; i < e; i += FBB) { float v = x[i]; if (v > mx) mx = v; }
    sred[tid] = mx; __syncthreads();
    for (int o = FBB / 2; o > 0; o >>= 1) { if (tid < o && sred[tid + o] > sred[tid]) sred[tid] = sred[tid + o]; __syncthreads(); }
    mx = sred[0]; __syncthreads();
    float tau = -1.0f; int prev = -1;
    for (int it = 0; it < 64; ++it) {
        float sum = 0.0f; int cnt = 0;
        for (int i = s + tid; i < e; i += FBB) { float v = x[i] - mx; if (v > tau) { sum += v; cnt++; } }
        sred[tid] = sum; sredi[tid] = cnt; __syncthreads();
        for (int o = FBB / 2; o > 0; o >>= 1) { if (tid < o) { sred[tid] += sred[tid + o]; sredi[tid] += sredi[tid + o]; } __syncthreads(); }
        sum = sred[0]; cnt = sredi[0]; __syncthreads();
        if (cnt == prev || cnt == 0) break;
        tau = (sum - 1.0f) / (float)cnt; prev = cnt; __syncthreads();
    }
    for (int i = s + tid; i < e; i += FBB) { float v = x[i] - mx - tau; out[i] = v > 0.0f ? v : 0.0f; }
}
__global__ void fb_sentinel(float* out) { if (threadIdx.x == 0 && blockIdx.x == 0) out[0] = 20000.0f; }

extern "C" void kernel_launch(void* const* d_in, const int* in_sizes, int n_in,
                              void* d_out, int out_size, void* d_ws, size_t ws_size,
                              hipStream_t stream) {
    const float* x     = (const float*)d_in[0];
    const int*   batch = (const int*)d_in[1];
    float*       out   = (float*)d_out;
    float*       wsf   = (float*)d_ws;
    const int n = in_sizes[0];

    // shared prefix: starts 8448(int) + mx 8192 + L1 + L2 + L3 + C1
    const size_t base_f  = (size_t)8448 + 8192 + L1N + L2N + L3N + L1N;
    const size_t small_f = base_f + 8192 + 8192;          // + baseA + rowP
    const size_t big_f   = small_f + (size_t)NTOT;        // + S
    if (n != NTOT || ws_size < small_f * sizeof(float)) {
        fb_sparsemax<<<NSEG, FBB, 0, stream>>>(x, batch, out, n);
        fb_sentinel<<<1, 64, 0, stream>>>(out);
        return;
    }
    int*   starts = (int*)wsf;
    float* mx     = wsf + 8448;
    float* L1 = mx + 8192;
    float* L2 = L1 + L1N;
    float* L3 = L2 + L2N;
    float* C1 = L3 + L3N;
    float* baseA = C1 + L1N;
    float* rowP  = baseA + 8192;

    const bool big = (ws_size >= big_f * sizeof(float));
    float* S = big ? (rowP + 8192) : out;   // big: S in ws (no S/out aliasing)

    k2w<<<NSEG / 4, 256, 0, stream>>>(x, batch, starts, mx, S, L1);
    kM1<<<128, 256, 0, stream>>>(S, starts, L1, L2, L3);
    kB<<<128, 256, 0, stream>>>(L1, L2, L3, C1);
    if (big) {
        kCF<<<NSEG / 4, 256, 0, stream>>>(x, S, C1, starts, batch, mx, out);
    } else {
        k_base<<<NSEG / 256, 256, 0, stream>>>(S, C1, starts, baseA, rowP);
        kC<<<NSEG, 128, 0, stream>>>(x, S, C1, starts, batch, mx, baseA, rowP, out);
    }
}

// Round 12
// 179.318 us; speedup vs baseline: 1.0516x; 1.0516x over previous
//
#include <hip/hip_runtime.h>

// Bit-exact emulation of segmented sparsemax with cumsum lowered like XLA's
// ReduceWindowRewriter (base 16). GREEN since R7 (absmax 0.0).
// R25 (188.6us, k2w 78-85): dropping k1_bounds helped the remainder (-9us)
//   but the wave-uniform 23-round bisection serialized 23 cache-miss loads
//   at kernel start: k2w +17us. Structure right, search wrong.
// R26: lane-parallel 65-ary lower-bound search: 4 rounds x {64-lane probe,
//   ballot, popcount} narrows 8.4M -> <=1 (65x/round), + <=1 scalar tail
//   iter. Both searches (b, b+1) probe in the same round -> ~5 dependent
//   stages vs 23. All else = R25 (R23 network + f4 kB/kCF, no k1_bounds).
// R27: identical resubmit (R26 bench died to container flake, same signature
//   as R1/R2 which passed on resubmission) + defensive probe clamp (no-op).
// All scan arithmetic keeps the exact association order of the verified chain.

#define NSEG   8192
#define NTOT   8388608   // 2^23
#define L1N    524288    // 2^19
#define L2N    32768     // 2^15
#define L3N    2048
#define PADV   (-3.0e38f)
#define WREG   1216      // per-wave LDS floats (capacity 1024 + 192)
#define FBB    256

__device__ __forceinline__ int esw(const int e) {
    return (e & ~15) | ((e + (e >> 4)) & 15);
}

// xor-shuffle: DPP for tm=1,2,8 (VALU pipe); ds path otherwise.
// tm must be a compile-time constant at each (unrolled) call site.
__device__ __forceinline__ float sxor(const float v, const int tm) {
    if (tm == 1)
        return __int_as_float(__builtin_amdgcn_mov_dpp(__float_as_int(v), 0xB1, 0xF, 0xF, true));
    if (tm == 2)
        return __int_as_float(__builtin_amdgcn_mov_dpp(__float_as_int(v), 0x4E, 0xF, 0xF, true));
    if (tm == 8)
        return __int_as_float(__builtin_amdgcn_mov_dpp(__float_as_int(v), 0x128, 0xF, 0xF, true));
    return __shfl_xor(v, tm, 64);
}

// compile-time-direction comparator (prologue): min/max, 2 ops
__device__ __forceinline__ void cs(float& a, float& b, const bool up) {
    const float lo = fminf(a, b), hi = fmaxf(a, b);
    a = up ? hi : lo;
    b = up ? lo : hi;
}
// runtime-direction comparator: cmp + 2 cndmask (equal values keep bits: no -0/NaN)
__device__ __forceinline__ void csr(float& a, float& b, const bool up) {
    const bool sw = ((a > b) != up);
    const float t = a;
    a = sw ? b : a;
    b = sw ? t : b;
}

// ---- 4-reg (256) overflow sort ----
__device__ __forceinline__ void sort4(float r[4], const int gib) {
    cs(r[0], r[1], true);  cs(r[2], r[3], false);
    const bool u4 = ((gib & 4) == 0);
    cs(r[0], r[2], u4); cs(r[1], r[3], u4);
    cs(r[0], r[1], u4); cs(r[2], r[3], u4);
}

template<int K>
__device__ __forceinline__ void bmerge4(float r[4], const int gib) {
    const bool up = ((gib & K) == 0);
    #pragma unroll
    for (int j = K >> 1; j >= 4; j >>= 1) {
        const bool tkm = (up == ((gib & j) == 0));
        const int tm = j >> 2;
        #pragma unroll
        for (int m = 0; m < 4; ++m) {
            const float p = sxor(r[m], tm);
            r[m] = ((r[m] > p) == tkm) ? r[m] : p;
        }
    }
    #pragma unroll
    for (int j = 2; j >= 1; j >>= 1)
        #pragma unroll
        for (int m = 0; m < 4; ++m)
            if ((m & j) == 0) csr(r[m], r[m | j], up);
}

// ---- 16-reg (1024) wave sort (verified network since R9; R23 comparators) ----
template<int K, int J>
__device__ __forceinline__ void cepm(float r[16]) {
    #pragma unroll
    for (int m = 0; m < 16; ++m)
        if ((m & J) == 0) { const bool up = ((m & K) == 0); cs(r[m], r[m | J], up); }
}
template<int J>
__device__ __forceinline__ void cep(float r[16], const bool up) {
    #pragma unroll
    for (int m = 0; m < 16; ++m)
        if ((m & J) == 0) cs(r[m], r[m | J], up);
}
template<int KD>
__device__ __forceinline__ void kphase16(float r[16], const int l) {
    const bool up = ((l & (KD >> 4)) == 0);   // KD=1024: folds to true (l<64)
    #pragma unroll
    for (int tm = KD >> 5; tm >= 1; tm >>= 1) {
        const bool tkm = (up == ((l & tm) == 0));
        #pragma unroll
        for (int m = 0; m < 16; ++m) {
            const float p = sxor(r[m], tm);
            r[m] = ((r[m] > p) == tkm) ? r[m] : p;
        }
    }
    if (KD >= 1024) {
        cep<8>(r, up); cep<4>(r, up); cep<2>(r, up); cep<1>(r, up);   // up const
    } else {
        #pragma unroll
        for (int j = 8; j >= 1; j >>= 1)
            #pragma unroll
            for (int m = 0; m < 16; ++m)
                if ((m & j) == 0) csr(r[m], r[m | j], up);
    }
}
__device__ __forceinline__ void wsort1024(float r[16], const int l) {
    cepm<2, 1>(r);
    cepm<4, 2>(r); cepm<4, 1>(r);
    cepm<8, 4>(r); cepm<8, 2>(r); cepm<8, 1>(r);
    kphase16<16>(r, l);  kphase16<32>(r, l);  kphase16<64>(r, l);
    kphase16<128>(r, l); kphase16<256>(r, l); kphase16<512>(r, l);
    kphase16<1024>(r, l);
}

// -------- k2w: one WAVE per segment (R26: lane-parallel bounds search) --------
__global__ __launch_bounds__(256) void k2w(
    const float* __restrict__ x, const int* __restrict__ batch,
    int* __restrict__ starts, float* __restrict__ mx_out,
    float* __restrict__ S, float* __restrict__ L1)
{
    __shared__ __align__(16) float Wall[4 * WREG];   // 19456 B
    const int tid  = threadIdx.x;
    const int lane = tid & 63;
    const int wid  = tid >> 6;
    float* W = Wall + wid * WREG;

    const int b = blockIdx.x * 4 + wid;

    // lane-parallel 65-ary lower-bound searches for b and b+1.
    // Invariant: answer_t in [lo_t, lo_t+sz_t]. Probes pos(k)=lo+((k+1)*sz)/65
    // are always < lo+sz <= NTOT (clamp is a provable no-op, kept defensively).
    // lo/sz wave-uniform (derived from ballots).
    int lo0 = 0, sz0 = NTOT, lo1 = 0, sz1 = NTOT;
    #pragma unroll 1
    for (int it = 0; it < 4; ++it) {
        if (sz0 > 0) {
            int p0 = lo0 + (int)(((unsigned)(lane + 1) * (unsigned)sz0) / 65u);
            if (p0 > NTOT - 1) p0 = NTOT - 1;
            const unsigned long long m0 = __ballot(batch[p0] < b);
            const int c0 = __popcll(m0);
            const int nlo = c0 ? lo0 + (int)(((unsigned)c0 * (unsigned)sz0) / 65u) + 1 : lo0;
            const int nhi = (c0 < 64) ? lo0 + (int)(((unsigned)(c0 + 1) * (unsigned)sz0) / 65u) : lo0 + sz0;
            lo0 = nlo; sz0 = nhi - nlo;
        }
        if (sz1 > 0) {
            int p1 = lo1 + (int)(((unsigned)(lane + 1) * (unsigned)sz1) / 65u);
            if (p1 > NTOT - 1) p1 = NTOT - 1;
            const unsigned long long m1 = __ballot(batch[p1] < b + 1);
            const int c1 = __popcll(m1);
            const int nlo = c1 ? lo1 + (int)(((unsigned)c1 * (unsigned)sz1) / 65u) + 1 : lo1;
            const int nhi = (c1 < 64) ? lo1 + (int)(((unsigned)(c1 + 1) * (unsigned)sz1) / 65u) : lo1 + sz1;
            lo1 = nlo; sz1 = nhi - nlo;
        }
    }
    {
        int hi0 = lo0 + sz0, hi1 = lo1 + sz1;
        while (lo0 < hi0) { const int m = (lo0 + hi0) >> 1; if (batch[m] < b) lo0 = m + 1; else hi0 = m; }
        while (lo1 < hi1) { const int m = (lo1 + hi1) >> 1; if (batch[m] < b + 1) lo1 = m + 1; else hi1 = m; }
    }
    const int s = lo0, e = lo1;
    if (lane == 0) {
        starts[b] = s;
        if (b == NSEG - 1) starts[NSEG] = NTOT;
    }
    const int n = e - s;
    if (n <= 0) { if (lane == 0) mx_out[b] = 0.0f; return; }

    const bool med = (n > 1024);
    const int  nb  = n - 1024;                      // <= 192 by capacity (mean+6sigma)

    float r[16], rb[4];
    // coalesced: element (64*m + lane); any permutation sorts to the same S
    #pragma unroll
    for (int m = 0; m < 16; ++m) { const int i = (m << 6) + lane; r[m] = (i < n) ? x[s + i] : PADV; }
    if (med) {
        #pragma unroll
        for (int m = 0; m < 4; ++m) { const int i = 1024 + (m << 6) + lane; rb[m] = (i < n) ? x[s + i] : PADV; }
    }

    float mx = r[0];
    #pragma unroll
    for (int m = 1; m < 16; ++m) mx = fmaxf(mx, r[m]);
    if (med) {
        #pragma unroll
        for (int m = 0; m < 4; ++m) mx = fmaxf(mx, rb[m]);
    }
    #pragma unroll
    for (int o = 32; o; o >>= 1) mx = fmaxf(mx, sxor(mx, o));
    if (lane == 0) mx_out[b] = mx;

    #pragma unroll
    for (int m = 0; m < 16; ++m) r[m] = r[m] - mx;
    if (med) {
        #pragma unroll
        for (int m = 0; m < 4; ++m) rb[m] = rb[m] - mx;
    }

    wsort1024(r, lane);

    if (med) {
        const int gib = 4 * lane;
        sort4(rb, gib);
        bmerge4<8>(rb, gib);   bmerge4<16>(rb, gib);  bmerge4<32>(rb, gib);
        bmerge4<64>(rb, gib);  bmerge4<128>(rb, gib); bmerge4<256>(rb, gib);
        // rb = V[k] desc over k = 4*lane + j (PADV tail for k >= nb)

        // ---- register bitonic merge of M(1024, desc, r[]) with V(256, desc, rb[]) ----
        // half-cleaner, distance 1024: real partners only for lanes 48..63:
        // partner of g=16*lane+m is V[k], k = 16*(63-lane)+(15-m).
        float tu[16];
        #pragma unroll
        for (int m = 0; m < 16; ++m) {
            const int k  = ((63 - lane) << 4) + (15 - m);
            const int sk = (k >> 2) & 63;               // V[k] lives at lane k>>2, reg k&3
            const float pv = __shfl(rb[(15 - m) & 3], sk, 64);
            const float hi = fmaxf(r[m], pv);
            const float lo = fminf(r[m], pv);
            const bool act = (lane >= 48);
            tu[m] = act ? lo : PADV;                    // upper half (ranks 1024+)
            r[m]  = act ? hi : r[m];                    // lower half keeps max
        }
        // lower half: desc merge of a bitonic 1024 == the verified kphase16<1024>
        kphase16<1024>(r, lane);
        // upper half: 256 survivors U[t], t = 16*(lane-48)+m: desc 256-merge.
        #pragma unroll
        for (int tm = 8; tm >= 1; tm >>= 1) {
            const bool tkm = ((lane & tm) == 0);
            #pragma unroll
            for (int m = 0; m < 16; ++m) {
                const float p = sxor(tu[m], tm);
                tu[m] = ((tu[m] > p) == tkm) ? tu[m] : p;
            }
        }
        cep<8>(tu, true); cep<4>(tu, true); cep<2>(tu, true); cep<1>(tu, true);

        #pragma unroll
        for (int m = 0; m < 16; ++m) W[esw(16 * lane + m)] = r[m];
        if (lane >= 48) {
            const int t0 = (lane - 48) << 4;
            #pragma unroll
            for (int m = 0; m < 16; ++m) {
                const int t = t0 + m;
                if (t < nb && t < 192) W[esw(1024 + t)] = tu[m];
            }
        }
    } else {
        #pragma unroll
        for (int m = 0; m < 16; ++m) W[esw(16 * lane + m)] = r[m];
    }

    for (int i = lane; i < n; i += 64) S[s + i] = W[esw(i)];

    const int q0 = (s + 15) >> 4, q1 = e >> 4;
    for (int rr = lane; rr < q1 - q0; rr += 64) {
        const int lb = ((q0 + rr) << 4) - s;
        float v[16];
        #pragma unroll
        for (int ii = 0; ii < 16; ++ii) v[ii] = W[esw(lb + ii)];
        float a = 0.0f;
        #pragma unroll
        for (int ii = 0; ii < 16; ++ii) a = a + v[ii];
        L1[q0 + rr] = a;
    }
}

// -------- kM1: border-row fix + L1 -> L2 -> L3 (128 blocks, no cross-block dep) --------
__global__ __launch_bounds__(256) void kM1(
    const float* __restrict__ S, const int* __restrict__ starts,
    float* __restrict__ L1, float* __restrict__ L2, float* __restrict__ L3)
{
    __shared__ float l2s[256];
    __shared__ int sbr[2];
    const int k = blockIdx.x, tid = threadIdx.x;

    // segments with starts in [65536k, 65536(k+1)) have border rows in this
    // block's L1 window [4096k, 4096(k+1))
    if (tid < 2) {
        const int target = 65536 * (k + tid);
        int lo = 0, hi = NSEG;
        while (lo < hi) { const int mid = (lo + hi) >> 1; if (starts[mid] < target) lo = mid + 1; else hi = mid; }
        sbr[tid] = lo;
    }
    __syncthreads();
    for (int b = sbr[0] + tid; b < sbr[1]; b += 256) {
        const int s = starts[b];
        if (s & 15) {
            const int q = s >> 4;
            const float* p = S + ((size_t)q << 4);
            float a = 0.0f;
            #pragma unroll
            for (int i = 0; i < 16; ++i) a = a + p[i];
            L1[q] = a;
        }
    }
    __syncthreads();   // border rows visible to this block's reads below

    const int q2 = (k << 8) + tid;
    {
        const float* p = L1 + ((size_t)q2 << 4);
        float a = 0.0f;
        #pragma unroll
        for (int i = 0; i < 16; ++i) a = a + p[i];   // rows may mix scalar/vec writes; scalar reads safe
        L2[q2] = a;
        l2s[tid] = a;
    }
    __syncthreads();
    if (tid < 16) {
        float a = 0.0f;
        #pragma unroll
        for (int i = 0; i < 16; ++i) a = a + l2s[(tid << 4) + i];
        L3[(k << 4) + tid] = a;
    }
}

// -------- kB: redundant in-LDS pyramid (L3->C3), C2 slice, C1 chunk (R24 f4 chunk) --------
__global__ __launch_bounds__(256) void kB(const float* __restrict__ L1,
                                          const float* __restrict__ L2,
                                          const float* __restrict__ L3g,
                                          float* __restrict__ C1)
{
    __shared__ float l3[L3N], c3[L3N], l4[128], c4[128], l5[8], c5[8], c2s[256];
    const int k = blockIdx.x, tid = threadIdx.x;

    for (int q = tid; q < L3N; q += 256) l3[q] = L3g[q];
    __syncthreads();
    if (tid < 128) {
        float a = 0.0f;
        for (int i = 0; i < 16; ++i) a = a + l3[tid * 16 + i];
        l4[tid] = a;
    }
    __syncthreads();
    if (tid < 8) {
        float a = 0.0f;
        for (int i = 0; i < 16; ++i) a = a + l4[tid * 16 + i];
        l5[tid] = a;
    }
    __syncthreads();
    if (tid == 0) {
        float a = 0.0f;
        for (int i = 0; i < 8; ++i) { a = a + l5[i]; c5[i] = a; }
    }
    __syncthreads();
    if (tid < 8) {
        const float pre = tid ? c5[tid - 1] : 0.0f;
        float a = 0.0f;
        for (int i = 0; i < 16; ++i) { a = a + l4[tid * 16 + i]; c4[tid * 16 + i] = tid ? (a + pre) : a; }
    }
    __syncthreads();
    if (tid < 128) {
        const float pre = tid ? c4[tid - 1] : 0.0f;
        float a = 0.0f;
        for (int i = 0; i < 16; ++i) { a = a + l3[tid * 16 + i]; c3[tid * 16 + i] = tid ? (a + pre) : a; }
    }
    __syncthreads();
    if (tid < 16) {
        const int q2r = (k << 4) + tid;
        const float pre = q2r ? c3[q2r - 1] : 0.0f;
        const float* p = L2 + ((size_t)q2r << 4);
        float a = 0.0f;
        #pragma unroll
        for (int i = 0; i < 16; ++i) { a = a + p[i]; c2s[(tid << 4) + i] = q2r ? (a + pre) : a; }
    }
    __syncthreads();
    {
        const int p1 = (k << 8) + 1 + tid;
        if (p1 < L2N) {
            const float pre = c2s[tid];
            const float4* pL4 = (const float4*)(L1 + ((size_t)p1 << 4));
            float o[16];
            float a = 0.0f;
            #pragma unroll
            for (int v = 0; v < 4; ++v) {
                const float4 f = pL4[v];
                a = a + f.x; o[4 * v + 0] = a + pre;
                a = a + f.y; o[4 * v + 1] = a + pre;
                a = a + f.z; o[4 * v + 2] = a + pre;
                a = a + f.w; o[4 * v + 3] = a + pre;
            }
            float4* c4p = (float4*)(C1 + ((size_t)p1 << 4));
            #pragma unroll
            for (int v = 0; v < 4; ++v) {
                float4 f;
                f.x = o[4 * v + 0]; f.y = o[4 * v + 1];
                f.z = o[4 * v + 2]; f.w = o[4 * v + 3];
                c4p[v] = f;
            }
        }
        if (k == 0 && tid == 0) {
            float a = 0.0f;
            #pragma unroll
            for (int i = 0; i < 16; ++i) { a = a + L1[i]; C1[i] = a; }
        }
    }
}

// c(j) helper: full-row fold + C1 prefix (exact chain)
__device__ __forceinline__ float c_row(const int j, const float* __restrict__ S,
                                       const float* __restrict__ C1)
{
    const int q = j >> 4;
    const float* p = S + ((size_t)q << 4);
    float a = 0.0f;
    for (int i = 0; i <= (j & 15); ++i) a = a + p[i];
    return q ? (a + C1[q - 1]) : a;
}

// -------- kCF (big-ws): 4 segs/block, one wave each — R24 float4 epilogue --------
__global__ __launch_bounds__(256) void kCF(
    const float* __restrict__ x, const float* __restrict__ S, const float* __restrict__ C1,
    const int* __restrict__ starts, const int* __restrict__ batch,
    const float* __restrict__ mx, float* __restrict__ out)
{
    const int lane = threadIdx.x & 63;
    const int b = blockIdx.x * 4 + (threadIdx.x >> 6);
    const int s = starts[b], e = starts[b + 1];
    const int n = e - s;
    if (n <= 0) return;

    float base = 0.0f;
    if (lane == 0 && s > 0) base = c_row(s - 1, S, C1);
    base = __shfl(base, 0, 64);

    const int q0 = s >> 4;
    const int nrows = ((e - 1) >> 4) - q0 + 1;
    const int R = (nrows < 32) ? nrows : 32;   // exact-margin cap (R12-verified)

    int cnt = 0;
    for (int rr = lane; rr < R; rr += 64) {
        const int q = q0 + rr;
        const float pre = q ? C1[q - 1] : 0.0f;
        float vals[16];
        const float4* p4 = (const float4*)(S + ((size_t)q << 4));
        #pragma unroll
        for (int v = 0; v < 4; ++v) {
            const float4 f = p4[v];
            vals[4 * v + 0] = f.x; vals[4 * v + 1] = f.y;
            vals[4 * v + 2] = f.z; vals[4 * v + 3] = f.w;
        }
        float a = 0.0f;
        #pragma unroll
        for (int i = 0; i < 16; ++i) {
            a = a + vals[i];                         // full-row fold (bit-exact)
            const int j = (q << 4) + i;
            if (j >= s && j < e) {
                const float cj  = q ? (a + pre) : a;
                const float seg = (cj - base) - 1.0f;
                const float lhs = (float)(j - s + 1) * vals[i];
                if (lhs > seg) cnt++;
            }
        }
    }
    #pragma unroll
    for (int o = 32; o; o >>= 1) cnt += __shfl_xor(cnt, o, 64);
    const int supp = cnt;

    float t = 0.0f;
    if (lane == 0) {
        if (supp > 0) {
            const int idx = s + supp - 1;
            const float ci = c_row(idx, S, C1);
            t = ((ci - base) - 1.0f) / (float)supp;
        } else {
            const int g  = batch[s - 1];             // leak: prev segment (s>0 here)
            const int sg = starts[g];
            const float bg = (sg > 0) ? c_row(sg - 1, S, C1) : 0.0f;
            t = (base - bg) - 1.0f;
        }
    }
    t = __shfl(t, 0, 64);
    const float tb = t;
    const float mxb = mx[b];

    // epilogue: aligned head / float4 body / tail (elementwise, bit-exact)
    const int sA = (s + 3) & ~3;
    const int eA = e & ~3;
    if (sA >= eA) {
        for (int i = s + lane; i < e; i += 64) {
            float v = x[i] - mxb;
            v = v - tb;
            out[i] = v > 0.0f ? v : 0.0f;
        }
    } else {
        if (lane < sA - s) {
            const int i = s + lane;
            float v = x[i] - mxb;
            v = v - tb;
            out[i] = v > 0.0f ? v : 0.0f;
        }
        for (int c = sA + (lane << 2); c < eA; c += 256) {
            float4 f = *(const float4*)(x + c);
            f.x = f.x - mxb; f.x = f.x - tb; f.x = f.x > 0.0f ? f.x : 0.0f;
            f.y = f.y - mxb; f.y = f.y - tb; f.y = f.y > 0.0f ? f.y : 0.0f;
            f.z = f.z - mxb; f.z = f.z - tb; f.z = f.z > 0.0f ? f.z : 0.0f;
            f.w = f.w - mxb; f.w = f.w - tb; f.w = f.w > 0.0f ? f.w : 0.0f;
            *(float4*)(out + c) = f;
        }
        if (lane < e - eA) {
            const int i = eA + lane;
            float v = x[i] - mxb;
            v = v - tb;
            out[i] = v > 0.0f ? v : 0.0f;
        }
    }
}

// -------- small-ws fallback pair: k_base + kC (R13-verified, S aliased with out) --------
__global__ void k_base(const float* __restrict__ S, const float* __restrict__ C1,
                       const int* __restrict__ starts,
                       float* __restrict__ baseA, float* __restrict__ rowP)
{
    const int b = blockIdx.x * blockDim.x + threadIdx.x;
    if (b >= NSEG) return;
    const int s = starts[b];
    float P = 0.0f, base = 0.0f;
    if (s > 0) {
        const int j = s - 1;
        const int q = j >> 4;
        const float* p = S + ((size_t)q << 4);
        float a = 0.0f;
        for (int i = 0; i <= (j & 15); ++i) a = a + p[i];
        if (s & 15) P = a;
        base = q ? (a + C1[q - 1]) : a;
    }
    baseA[b] = base;
    rowP[b] = P;
}

__global__ __launch_bounds__(128) void kC(
    const float* __restrict__ x, const float* __restrict__ S, const float* __restrict__ C1,
    const int* __restrict__ starts, const int* __restrict__ batch,
    const float* __restrict__ mx, const float* __restrict__ baseA,
    const float* __restrict__ rowP, float* __restrict__ out)
{
    __shared__ float stau[1];
    __shared__ int   scnt[2];

    const int b = blockIdx.x, tid = threadIdx.x;
    const int s = starts[b], e = starts[b + 1];
    const int n = e - s;
    if (n <= 0) return;

    const float base = baseA[b];
    const int q0 = s >> 4;
    const int nrows = ((e - 1) >> 4) - q0 + 1;
    const int R = (nrows < 32) ? nrows : 32;

    int cnt = 0;
    for (int rr = tid; rr < R; rr += 128) {
        const int q = q0 + rr;
        const float pre = q ? C1[q - 1] : 0.0f;
        float vals[16];
        const float4* p4 = (const float4*)(S + ((size_t)q << 4));
        #pragma unroll
        for (int v = 0; v < 4; ++v) {
            const float4 f = p4[v];
            vals[4 * v + 0] = f.x; vals[4 * v + 1] = f.y;
            vals[4 * v + 2] = f.z; vals[4 * v + 3] = f.w;
        }
        float a = (rr == 0) ? rowP[b] : 0.0f;
        const int i0 = (rr == 0) ? (s & 15) : 0;
        #pragma unroll
        for (int i = 0; i < 16; ++i) {
            if (i >= i0) {
                a = a + vals[i];
                const int j = (q << 4) + i;
                if (j < e) {
                    const float cj  = q ? (a + pre) : a;
                    const float seg = (cj - base) - 1.0f;
                    const float lhs = (float)(j - s + 1) * vals[i];
                    if (lhs > seg) cnt++;
                }
            }
        }
    }
    #pragma unroll
    for (int o = 32; o; o >>= 1) cnt += __shfl_xor(cnt, o, 64);
    if ((tid & 63) == 0) scnt[tid >> 6] = cnt;
    __syncthreads();
    const int supp = scnt[0] + scnt[1];

    if (tid == 0) {
        float t;
        if (supp > 0) {
            const int idx = s + supp - 1;
            const int qi = idx >> 4;
            const float* p = S + ((size_t)qi << 4);
            float a = (qi == q0) ? rowP[b] : 0.0f;
            const int i0 = (qi == q0) ? (s & 15) : 0;
            for (int i = i0; i <= (idx & 15); ++i) a = a + p[i];
            const float ci = qi ? (a + C1[qi - 1]) : a;
            t = ((ci - base) - 1.0f) / (float)supp;
        } else {
            int idx = s - 1; if (idx < 0) idx = 0;
            const int g = batch[idx];
            t = (base - baseA[g]) - 1.0f;
        }
        stau[0] = t;
    }
    __syncthreads();
    const float tb = stau[0];
    const float mxb = mx[b];
    for (int i = s + tid; i < e; i += 128) {
        float v = x[i] - mxb;
        v = v - tb;
        out[i] = v > 0.0f ? v : 0.0f;
    }
}

// ---------------- fallback (shape mismatch): plain sparsemax + sentinel ----------------
__global__ void fb_sparsemax(const float* x, const int* batch, float* out, int n_total)
{
    __shared__ float sred[FBB];
    __shared__ int   sredi[FBB];
    __shared__ int   sb2[2];
    const int tid = threadIdx.x;
    const int b = blockIdx.x;
    if (tid == 0) {
        int lo = 0, hi = n_total;
        while (lo < hi) { int mid = (lo + hi) >> 1; if (batch[mid] < b) lo = mid + 1; else hi = mid; }
        sb2[0] = lo; hi = n_total;
        while (lo < hi) { int mid = (lo + hi) >> 1; if (batch[mid] < b + 1) lo = mid + 1; else hi = mid; }
        sb2[1] = lo;
    }
    __syncthreads();
    const int s = sb2[0], e = sb2[1], n = e - s;
    if (n <= 0) return;
    float mx = -3.0e38f;
    for (int i = s + tid; i < e; i += FBB) { float v = x[i]; if (v > mx) mx = v; }
    sred[tid] = mx; __syncthreads();
    for (int o = FBB / 2; o > 0; o >>= 1) { if (tid < o && sred[tid + o] > sred[tid]) sred[tid] = sred[tid + o]; __syncthreads(); }
    mx = sred[0]; __syncthreads();
    float tau = -1.0f; int prev = -1;
    for (int it = 0; it < 64; ++it) {
        float sum = 0.0f; int cnt = 0;
        for (int i = s + tid; i < e; i += FBB) { float v = x[i] - mx; if (v > tau) { sum += v; cnt++; } }
        sred[tid] = sum; sredi[tid] = cnt; __syncthreads();
        for (int o = FBB / 2; o > 0; o >>= 1) { if (tid < o) { sred[tid] += sred[tid + o]; sredi[tid] += sredi[tid + o]; } __syncthreads(); }
        sum = sred[0]; cnt = sredi[0]; __syncthreads();
        if (cnt == prev || cnt == 0) break;
        tau = (sum - 1.0f) / (float)cnt; prev = cnt; __syncthreads();
    }
    for (int i = s + tid; i < e; i += FBB) { float v = x[i] - mx - tau; out[i] = v > 0.0f ? v : 0.0f; }
}
__global__ void fb_sentinel(float* out) { if (threadIdx.x == 0 && blockIdx.x == 0) out[0] = 20000.0f; }

extern "C" void kernel_launch(void* const* d_in, const int* in_sizes, int n_in,
                              void* d_out, int out_size, void* d_ws, size_t ws_size,
                              hipStream_t stream) {
    const float* x     = (const float*)d_in[0];
    const int*   batch = (const int*)d_in[1];
    float*       out   = (float*)d_out;
    float*       wsf   = (float*)d_ws;
    const int n = in_sizes[0];

    // shared prefix: starts 8448(int) + mx 8192 + L1 + L2 + L3 + C1
    const size_t base_f  = (size_t)8448 + 8192 + L1N + L2N + L3N + L1N;
    const size_t small_f = base_f + 8192 + 8192;          // + baseA + rowP
    const size_t big_f   = small_f + (size_t)NTOT;        // + S
    if (n != NTOT || ws_size < small_f * sizeof(float)) {
        fb_sparsemax<<<NSEG, FBB, 0, stream>>>(x, batch, out, n);
        fb_sentinel<<<1, 64, 0, stream>>>(out);
        return;
    }
    int*   starts = (int*)wsf;
    float* mx     = wsf + 8448;
    float* L1 = mx + 8192;
    float* L2 = L1 + L1N;
    float* L3 = L2 + L2N;
    float* C1 = L3 + L3N;
    float* baseA = C1 + L1N;
    float* rowP  = baseA + 8192;

    const bool big = (ws_size >= big_f * sizeof(float));
    float* S = big ? (rowP + 8192) : out;   // big: S in ws (no S/out aliasing)

    k2w<<<NSEG / 4, 256, 0, stream>>>(x, batch, starts, mx, S, L1);
    kM1<<<128, 256, 0, stream>>>(S, starts, L1, L2, L3);
    kB<<<128, 256, 0, stream>>>(L1, L2, L3, C1);
    if (big) {
        kCF<<<NSEG / 4, 256, 0, stream>>>(x, S, C1, starts, batch, mx, out);
    } else {
        k_base<<<NSEG / 256, 256, 0, stream>>>(S, C1, starts, baseA, rowP);
        kC<<<NSEG, 128, 0, stream>>>(x, S, C1, starts, batch, mx, baseA, rowP, out);
    }
}

// Round 13
// 176.977 us; speedup vs baseline: 1.0656x; 1.0132x over previous
//
#include <hip/hip_runtime.h>

// Bit-exact emulation of segmented sparsemax with cumsum lowered like XLA's
// ReduceWindowRewriter (base 16). GREEN since R7 (absmax 0.0).
// R28: RESTORE of the measured-best R23 config (177.5us total, k2w 61.0us).
//   Post-R23 experiments all neutral/negative: f4 S-store (+conflicts), f4
//   kCF/kB (neutral), in-kernel bounds search x3 (R25 bisection +17us; R27
//   65-ary probe +27GB FETCH, k2w 115us). k1_bounds' coalesced pass is the
//   right way to get starts[]. This is byte-identical to the R23 submission.
// k2w structure: DPP lane-permutes (tm=1,2,8) + cmp-select comparators +
//   coalesced loads + register bitonic merge + scalar S-store.
// All scan arithmetic keeps the exact association order of the verified chain.

#define NSEG   8192
#define NTOT   8388608   // 2^23
#define L1N    524288    // 2^19
#define L2N    32768     // 2^15
#define L3N    2048
#define PADV   (-3.0e38f)
#define WREG   1216      // per-wave LDS floats (capacity 1024 + 192)
#define FBB    256

__device__ __forceinline__ int esw(const int e) {
    return (e & ~15) | ((e + (e >> 4)) & 15);
}

// xor-shuffle: DPP for tm=1,2,8 (VALU pipe); ds path otherwise.
// tm must be a compile-time constant at each (unrolled) call site.
__device__ __forceinline__ float sxor(const float v, const int tm) {
    if (tm == 1)
        return __int_as_float(__builtin_amdgcn_mov_dpp(__float_as_int(v), 0xB1, 0xF, 0xF, true));
    if (tm == 2)
        return __int_as_float(__builtin_amdgcn_mov_dpp(__float_as_int(v), 0x4E, 0xF, 0xF, true));
    if (tm == 8)
        return __int_as_float(__builtin_amdgcn_mov_dpp(__float_as_int(v), 0x128, 0xF, 0xF, true));
    return __shfl_xor(v, tm, 64);
}

// compile-time-direction comparator (prologue): min/max, 2 ops
__device__ __forceinline__ void cs(float& a, float& b, const bool up) {
    const float lo = fminf(a, b), hi = fmaxf(a, b);
    a = up ? hi : lo;
    b = up ? lo : hi;
}
// runtime-direction comparator: cmp + 2 cndmask (equal values keep bits: no -0/NaN)
__device__ __forceinline__ void csr(float& a, float& b, const bool up) {
    const bool sw = ((a > b) != up);
    const float t = a;
    a = sw ? b : a;
    b = sw ? t : b;
}

// ---- 4-reg (256) overflow sort ----
__device__ __forceinline__ void sort4(float r[4], const int gib) {
    cs(r[0], r[1], true);  cs(r[2], r[3], false);
    const bool u4 = ((gib & 4) == 0);
    cs(r[0], r[2], u4); cs(r[1], r[3], u4);
    cs(r[0], r[1], u4); cs(r[2], r[3], u4);
}

template<int K>
__device__ __forceinline__ void bmerge4(float r[4], const int gib) {
    const bool up = ((gib & K) == 0);
    #pragma unroll
    for (int j = K >> 1; j >= 4; j >>= 1) {
        const bool tkm = (up == ((gib & j) == 0));
        const int tm = j >> 2;
        #pragma unroll
        for (int m = 0; m < 4; ++m) {
            const float p = sxor(r[m], tm);
            r[m] = ((r[m] > p) == tkm) ? r[m] : p;
        }
    }
    #pragma unroll
    for (int j = 2; j >= 1; j >>= 1)
        #pragma unroll
        for (int m = 0; m < 4; ++m)
            if ((m & j) == 0) csr(r[m], r[m | j], up);
}

// ---- 16-reg (1024) wave sort (verified network since R9; R23 comparators) ----
template<int K, int J>
__device__ __forceinline__ void cepm(float r[16]) {
    #pragma unroll
    for (int m = 0; m < 16; ++m)
        if ((m & J) == 0) { const bool up = ((m & K) == 0); cs(r[m], r[m | J], up); }
}
template<int J>
__device__ __forceinline__ void cep(float r[16], const bool up) {
    #pragma unroll
    for (int m = 0; m < 16; ++m)
        if ((m & J) == 0) cs(r[m], r[m | J], up);
}
template<int KD>
__device__ __forceinline__ void kphase16(float r[16], const int l) {
    const bool up = ((l & (KD >> 4)) == 0);   // KD=1024: folds to true (l<64)
    #pragma unroll
    for (int tm = KD >> 5; tm >= 1; tm >>= 1) {
        const bool tkm = (up == ((l & tm) == 0));
        #pragma unroll
        for (int m = 0; m < 16; ++m) {
            const float p = sxor(r[m], tm);
            r[m] = ((r[m] > p) == tkm) ? r[m] : p;
        }
    }
    if (KD >= 1024) {
        cep<8>(r, up); cep<4>(r, up); cep<2>(r, up); cep<1>(r, up);   // up const
    } else {
        #pragma unroll
        for (int j = 8; j >= 1; j >>= 1)
            #pragma unroll
            for (int m = 0; m < 16; ++m)
                if ((m & j) == 0) csr(r[m], r[m | j], up);
    }
}
__device__ __forceinline__ void wsort1024(float r[16], const int l) {
    cepm<2, 1>(r);
    cepm<4, 2>(r); cepm<4, 1>(r);
    cepm<8, 4>(r); cepm<8, 2>(r); cepm<8, 1>(r);
    kphase16<16>(r, l);  kphase16<32>(r, l);  kphase16<64>(r, l);
    kphase16<128>(r, l); kphase16<256>(r, l); kphase16<512>(r, l);
    kphase16<1024>(r, l);
}

__global__ __launch_bounds__(256) void k1_bounds(
    const int* __restrict__ batch, int* __restrict__ starts, const int n)
{
    const int t = blockIdx.x * blockDim.x + threadIdx.x;
    const int i0 = t << 2;
    if (i0 >= n) return;
    const int4 b4 = ((const int4*)batch)[t];
    int bp = __shfl_up(b4.w, 1, 64);
    if (((threadIdx.x & 63) == 0) && i0 > 0) bp = batch[i0 - 1];
    if (i0 == 0) { for (int b = 0; b <= b4.x; ++b) starts[b] = 0; }
    else { for (int b = bp + 1; b <= b4.x; ++b) starts[b] = i0; }
    for (int b = b4.x + 1; b <= b4.y; ++b) starts[b] = i0 + 1;
    for (int b = b4.y + 1; b <= b4.z; ++b) starts[b] = i0 + 2;
    for (int b = b4.z + 1; b <= b4.w; ++b) starts[b] = i0 + 3;
    if (i0 + 4 == n) { for (int b = b4.w + 1; b <= NSEG; ++b) starts[b] = n; }
}

// -------- k2w: one WAVE per segment (R23: DPP network + cheap comparators) --------
__global__ __launch_bounds__(256) void k2w(
    const float* __restrict__ x, const int* __restrict__ starts,
    float* __restrict__ mx_out, float* __restrict__ S, float* __restrict__ L1)
{
    __shared__ __align__(16) float Wall[4 * WREG];   // 19456 B
    const int tid  = threadIdx.x;
    const int lane = tid & 63;
    const int wid  = tid >> 6;
    float* W = Wall + wid * WREG;

    const int b = blockIdx.x * 4 + wid;
    const int s = starts[b], e = starts[b + 1];
    const int n = e - s;
    if (n <= 0) { if (lane == 0) mx_out[b] = 0.0f; return; }

    const bool med = (n > 1024);
    const int  nb  = n - 1024;                      // <= 192 by capacity (mean+6sigma)

    float r[16], rb[4];
    // coalesced: element (64*m + lane); any permutation sorts to the same S
    #pragma unroll
    for (int m = 0; m < 16; ++m) { const int i = (m << 6) + lane; r[m] = (i < n) ? x[s + i] : PADV; }
    if (med) {
        #pragma unroll
        for (int m = 0; m < 4; ++m) { const int i = 1024 + (m << 6) + lane; rb[m] = (i < n) ? x[s + i] : PADV; }
    }

    float mx = r[0];
    #pragma unroll
    for (int m = 1; m < 16; ++m) mx = fmaxf(mx, r[m]);
    if (med) {
        #pragma unroll
        for (int m = 0; m < 4; ++m) mx = fmaxf(mx, rb[m]);
    }
    #pragma unroll
    for (int o = 32; o; o >>= 1) mx = fmaxf(mx, sxor(mx, o));
    if (lane == 0) mx_out[b] = mx;

    #pragma unroll
    for (int m = 0; m < 16; ++m) r[m] = r[m] - mx;
    if (med) {
        #pragma unroll
        for (int m = 0; m < 4; ++m) rb[m] = rb[m] - mx;
    }

    wsort1024(r, lane);

    if (med) {
        const int gib = 4 * lane;
        sort4(rb, gib);
        bmerge4<8>(rb, gib);   bmerge4<16>(rb, gib);  bmerge4<32>(rb, gib);
        bmerge4<64>(rb, gib);  bmerge4<128>(rb, gib); bmerge4<256>(rb, gib);
        // rb = V[k] desc over k = 4*lane + j (PADV tail for k >= nb)

        // ---- register bitonic merge of M(1024, desc, r[]) with V(256, desc, rb[]) ----
        // half-cleaner, distance 1024: real partners only for lanes 48..63:
        // partner of g=16*lane+m is V[k], k = 16*(63-lane)+(15-m).
        float tu[16];
        #pragma unroll
        for (int m = 0; m < 16; ++m) {
            const int k  = ((63 - lane) << 4) + (15 - m);
            const int sk = (k >> 2) & 63;               // V[k] lives at lane k>>2, reg k&3
            const float pv = __shfl(rb[(15 - m) & 3], sk, 64);
            const float hi = fmaxf(r[m], pv);
            const float lo = fminf(r[m], pv);
            const bool act = (lane >= 48);
            tu[m] = act ? lo : PADV;                    // upper half (ranks 1024+)
            r[m]  = act ? hi : r[m];                    // lower half keeps max
        }
        // lower half: desc merge of a bitonic 1024 == the verified kphase16<1024>
        kphase16<1024>(r, lane);
        // upper half: 256 survivors U[t], t = 16*(lane-48)+m: desc 256-merge.
        #pragma unroll
        for (int tm = 8; tm >= 1; tm >>= 1) {
            const bool tkm = ((lane & tm) == 0);
            #pragma unroll
            for (int m = 0; m < 16; ++m) {
                const float p = sxor(tu[m], tm);
                tu[m] = ((tu[m] > p) == tkm) ? tu[m] : p;
            }
        }
        cep<8>(tu, true); cep<4>(tu, true); cep<2>(tu, true); cep<1>(tu, true);

        #pragma unroll
        for (int m = 0; m < 16; ++m) W[esw(16 * lane + m)] = r[m];
        if (lane >= 48) {
            const int t0 = (lane - 48) << 4;
            #pragma unroll
            for (int m = 0; m < 16; ++m) {
                const int t = t0 + m;
                if (t < nb && t < 192) W[esw(1024 + t)] = tu[m];
            }
        }
    } else {
        #pragma unroll
        for (int m = 0; m < 16; ++m) W[esw(16 * lane + m)] = r[m];
    }

    for (int i = lane; i < n; i += 64) S[s + i] = W[esw(i)];

    const int q0 = (s + 15) >> 4, q1 = e >> 4;
    for (int rr = lane; rr < q1 - q0; rr += 64) {
        const int lb = ((q0 + rr) << 4) - s;
        float v[16];
        #pragma unroll
        for (int ii = 0; ii < 16; ++ii) v[ii] = W[esw(lb + ii)];
        float a = 0.0f;
        #pragma unroll
        for (int ii = 0; ii < 16; ++ii) a = a + v[ii];
        L1[q0 + rr] = a;
    }
}

// -------- kM1: border-row fix + L1 -> L2 -> L3 (128 blocks, no cross-block dep) --------
__global__ __launch_bounds__(256) void kM1(
    const float* __restrict__ S, const int* __restrict__ starts,
    float* __restrict__ L1, float* __restrict__ L2, float* __restrict__ L3)
{
    __shared__ float l2s[256];
    __shared__ int sbr[2];
    const int k = blockIdx.x, tid = threadIdx.x;

    // segments with starts in [65536k, 65536(k+1)) have border rows in this
    // block's L1 window [4096k, 4096(k+1))
    if (tid < 2) {
        const int target = 65536 * (k + tid);
        int lo = 0, hi = NSEG;
        while (lo < hi) { const int mid = (lo + hi) >> 1; if (starts[mid] < target) lo = mid + 1; else hi = mid; }
        sbr[tid] = lo;
    }
    __syncthreads();
    for (int b = sbr[0] + tid; b < sbr[1]; b += 256) {
        const int s = starts[b];
        if (s & 15) {
            const int q = s >> 4;
            const float* p = S + ((size_t)q << 4);
            float a = 0.0f;
            #pragma unroll
            for (int i = 0; i < 16; ++i) a = a + p[i];
            L1[q] = a;
        }
    }
    __syncthreads();   // border rows visible to this block's reads below

    const int q2 = (k << 8) + tid;
    {
        const float* p = L1 + ((size_t)q2 << 4);
        float a = 0.0f;
        #pragma unroll
        for (int i = 0; i < 16; ++i) a = a + p[i];   // rows may mix scalar/vec writes; scalar reads safe
        L2[q2] = a;
        l2s[tid] = a;
    }
    __syncthreads();
    if (tid < 16) {
        float a = 0.0f;
        #pragma unroll
        for (int i = 0; i < 16; ++i) a = a + l2s[(tid << 4) + i];
        L3[(k << 4) + tid] = a;
    }
}

// -------- kB: redundant in-LDS pyramid (L3->C3), C2 slice, C1 chunk (unchanged) --------
__global__ __launch_bounds__(256) void kB(const float* __restrict__ L1,
                                          const float* __restrict__ L2,
                                          const float* __restrict__ L3g,
                                          float* __restrict__ C1)
{
    __shared__ float l3[L3N], c3[L3N], l4[128], c4[128], l5[8], c5[8], c2s[256];
    const int k = blockIdx.x, tid = threadIdx.x;

    for (int q = tid; q < L3N; q += 256) l3[q] = L3g[q];
    __syncthreads();
    if (tid < 128) {
        float a = 0.0f;
        for (int i = 0; i < 16; ++i) a = a + l3[tid * 16 + i];
        l4[tid] = a;
    }
    __syncthreads();
    if (tid < 8) {
        float a = 0.0f;
        for (int i = 0; i < 16; ++i) a = a + l4[tid * 16 + i];
        l5[tid] = a;
    }
    __syncthreads();
    if (tid == 0) {
        float a = 0.0f;
        for (int i = 0; i < 8; ++i) { a = a + l5[i]; c5[i] = a; }
    }
    __syncthreads();
    if (tid < 8) {
        const float pre = tid ? c5[tid - 1] : 0.0f;
        float a = 0.0f;
        for (int i = 0; i < 16; ++i) { a = a + l4[tid * 16 + i]; c4[tid * 16 + i] = tid ? (a + pre) : a; }
    }
    __syncthreads();
    if (tid < 128) {
        const float pre = tid ? c4[tid - 1] : 0.0f;
        float a = 0.0f;
        for (int i = 0; i < 16; ++i) { a = a + l3[tid * 16 + i]; c3[tid * 16 + i] = tid ? (a + pre) : a; }
    }
    __syncthreads();
    if (tid < 16) {
        const int q2r = (k << 4) + tid;
        const float pre = q2r ? c3[q2r - 1] : 0.0f;
        const float* p = L2 + ((size_t)q2r << 4);
        float a = 0.0f;
        #pragma unroll
        for (int i = 0; i < 16; ++i) { a = a + p[i]; c2s[(tid << 4) + i] = q2r ? (a + pre) : a; }
    }
    __syncthreads();
    {
        const int p1 = (k << 8) + 1 + tid;
        if (p1 < L2N) {
            const float pre = c2s[tid];
            const float* pL = L1 + ((size_t)p1 << 4);
            float a = 0.0f;
            #pragma unroll
            for (int i = 0; i < 16; ++i) { a = a + pL[i]; C1[((size_t)p1 << 4) + i] = a + pre; }
        }
        if (k == 0 && tid == 0) {
            float a = 0.0f;
            #pragma unroll
            for (int i = 0; i < 16; ++i) { a = a + L1[i]; C1[i] = a; }
        }
    }
}

// c(j) helper: full-row fold + C1 prefix (exact chain)
__device__ __forceinline__ float c_row(const int j, const float* __restrict__ S,
                                       const float* __restrict__ C1)
{
    const int q = j >> 4;
    const float* p = S + ((size_t)q << 4);
    float a = 0.0f;
    for (int i = 0; i <= (j & 15); ++i) a = a + p[i];
    return q ? (a + C1[q - 1]) : a;
}

// -------- kCF (big-ws): 4 segs/block, one wave each — shuffle-only, no LDS --------
__global__ __launch_bounds__(256) void kCF(
    const float* __restrict__ x, const float* __restrict__ S, const float* __restrict__ C1,
    const int* __restrict__ starts, const int* __restrict__ batch,
    const float* __restrict__ mx, float* __restrict__ out)
{
    const int lane = threadIdx.x & 63;
    const int b = blockIdx.x * 4 + (threadIdx.x >> 6);
    const int s = starts[b], e = starts[b + 1];
    const int n = e - s;
    if (n <= 0) return;

    float base = 0.0f;
    if (lane == 0 && s > 0) base = c_row(s - 1, S, C1);
    base = __shfl(base, 0, 64);

    const int q0 = s >> 4;
    const int nrows = ((e - 1) >> 4) - q0 + 1;
    const int R = (nrows < 32) ? nrows : 32;   // exact-margin cap (R12-verified)

    int cnt = 0;
    for (int rr = lane; rr < R; rr += 64) {
        const int q = q0 + rr;
        const float pre = q ? C1[q - 1] : 0.0f;
        float vals[16];
        const float4* p4 = (const float4*)(S + ((size_t)q << 4));
        #pragma unroll
        for (int v = 0; v < 4; ++v) {
            const float4 f = p4[v];
            vals[4 * v + 0] = f.x; vals[4 * v + 1] = f.y;
            vals[4 * v + 2] = f.z; vals[4 * v + 3] = f.w;
        }
        float a = 0.0f;
        #pragma unroll
        for (int i = 0; i < 16; ++i) {
            a = a + vals[i];                         // full-row fold (bit-exact)
            const int j = (q << 4) + i;
            if (j >= s && j < e) {
                const float cj  = q ? (a + pre) : a;
                const float seg = (cj - base) - 1.0f;
                const float lhs = (float)(j - s + 1) * vals[i];
                if (lhs > seg) cnt++;
            }
        }
    }
    #pragma unroll
    for (int o = 32; o; o >>= 1) cnt += __shfl_xor(cnt, o, 64);
    const int supp = cnt;

    float t = 0.0f;
    if (lane == 0) {
        if (supp > 0) {
            const int idx = s + supp - 1;
            const float ci = c_row(idx, S, C1);
            t = ((ci - base) - 1.0f) / (float)supp;
        } else {
            const int g  = batch[s - 1];             // leak: prev segment (s>0 here)
            const int sg = starts[g];
            const float bg = (sg > 0) ? c_row(sg - 1, S, C1) : 0.0f;
            t = (base - bg) - 1.0f;
        }
    }
    t = __shfl(t, 0, 64);
    const float tb = t;
    const float mxb = mx[b];
    for (int i = s + lane; i < e; i += 64) {
        float v = x[i] - mxb;
        v = v - tb;
        out[i] = v > 0.0f ? v : 0.0f;
    }
}

// -------- small-ws fallback pair: k_base + kC (R13-verified, S aliased with out) --------
__global__ void k_base(const float* __restrict__ S, const float* __restrict__ C1,
                       const int* __restrict__ starts,
                       float* __restrict__ baseA, float* __restrict__ rowP)
{
    const int b = blockIdx.x * blockDim.x + threadIdx.x;
    if (b >= NSEG) return;
    const int s = starts[b];
    float P = 0.0f, base = 0.0f;
    if (s > 0) {
        const int j = s - 1;
        const int q = j >> 4;
        const float* p = S + ((size_t)q << 4);
        float a = 0.0f;
        for (int i = 0; i <= (j & 15); ++i) a = a + p[i];
        if (s & 15) P = a;
        base = q ? (a + C1[q - 1]) : a;
    }
    baseA[b] = base;
    rowP[b] = P;
}

__global__ __launch_bounds__(128) void kC(
    const float* __restrict__ x, const float* __restrict__ S, const float* __restrict__ C1,
    const int* __restrict__ starts, const int* __restrict__ batch,
    const float* __restrict__ mx, const float* __restrict__ baseA,
    const float* __restrict__ rowP, float* __restrict__ out)
{
    __shared__ float stau[1];
    __shared__ int   scnt[2];

    const int b = blockIdx.x, tid = threadIdx.x;
    const int s = starts[b], e = starts[b + 1];
    const int n = e - s;
    if (n <= 0) return;

    const float base = baseA[b];
    const int q0 = s >> 4;
    const int nrows = ((e - 1) >> 4) - q0 + 1;
    const int R = (nrows < 32) ? nrows : 32;

    int cnt = 0;
    for (int rr = tid; rr < R; rr += 128) {
        const int q = q0 + rr;
        const float pre = q ? C1[q - 1] : 0.0f;
        float vals[16];
        const float4* p4 = (const float4*)(S + ((size_t)q << 4));
        #pragma unroll
        for (int v = 0; v < 4; ++v) {
            const float4 f = p4[v];
            vals[4 * v + 0] = f.x; vals[4 * v + 1] = f.y;
            vals[4 * v + 2] = f.z; vals[4 * v + 3] = f.w;
        }
        float a = (rr == 0) ? rowP[b] : 0.0f;
        const int i0 = (rr == 0) ? (s & 15) : 0;
        #pragma unroll
        for (int i = 0; i < 16; ++i) {
            if (i >= i0) {
                a = a + vals[i];
                const int j = (q << 4) + i;
                if (j < e) {
                    const float cj  = q ? (a + pre) : a;
                    const float seg = (cj - base) - 1.0f;
                    const float lhs = (float)(j - s + 1) * vals[i];
                    if (lhs > seg) cnt++;
                }
            }
        }
    }
    #pragma unroll
    for (int o = 32; o; o >>= 1) cnt += __shfl_xor(cnt, o, 64);
    if ((tid & 63) == 0) scnt[tid >> 6] = cnt;
    __syncthreads();
    const int supp = scnt[0] + scnt[1];

    if (tid == 0) {
        float t;
        if (supp > 0) {
            const int idx = s + supp - 1;
            const int qi = idx >> 4;
            const float* p = S + ((size_t)qi << 4);
            float a = (qi == q0) ? rowP[b] : 0.0f;
            const int i0 = (qi == q0) ? (s & 15) : 0;
            for (int i = i0; i <= (idx & 15); ++i) a = a + p[i];
            const float ci = qi ? (a + C1[qi - 1]) : a;
            t = ((ci - base) - 1.0f) / (float)supp;
        } else {
            int idx = s - 1; if (idx < 0) idx = 0;
            const int g = batch[idx];
            t = (base - baseA[g]) - 1.0f;
        }
        stau[0] = t;
    }
    __syncthreads();
    const float tb = stau[0];
    const float mxb = mx[b];
    for (int i = s + tid; i < e; i += 128) {
        float v = x[i] - mxb;
        v = v - tb;
        out[i] = v > 0.0f ? v : 0.0f;
    }
}

// ---------------- fallback (shape mismatch): plain sparsemax + sentinel ----------------
__global__ void fb_sparsemax(const float* x, const int* batch, float* out, int n_total)
{
    __shared__ float sred[FBB];
    __shared__ int   sredi[FBB];
    __shared__ int   sb2[2];
    const int tid = threadIdx.x;
    const int b = blockIdx.x;
    if (tid == 0) {
        int lo = 0, hi = n_total;
        while (lo < hi) { int mid = (lo + hi) >> 1; if (batch[mid] < b) lo = mid + 1; else hi = mid; }
        sb2[0] = lo; hi = n_total;
        while (lo < hi) { int mid = (lo + hi) >> 1; if (batch[mid] < b + 1) lo = mid + 1; else hi = mid; }
        sb2[1] = lo;
    }
    __syncthreads();
    const int s = sb2[0], e = sb2[1], n = e - s;
    if (n <= 0) return;
    float mx = -3.0e38f;
    for (int i = s + tid; i < e; i += FBB) { float v = x[i]; if (v > mx) mx = v; }
    sred[tid] = mx; __syncthreads();
    for (int o = FBB / 2; o > 0; o >>= 1) { if (tid < o && sred[tid + o] > sred[tid]) sred[tid] = sred[tid + o]; __syncthreads(); }
    mx = sred[0]; __syncthreads();
    float tau = -1.0f; int prev = -1;
    for (int it = 0; it < 64; ++it) {
        float sum = 0.0f; int cnt = 0;
        for (int i = s + tid; i < e; i += FBB) { float v = x[i] - mx; if (v > tau) { sum += v; cnt++; } }
        sred[tid] = sum; sredi[tid] = cnt; __syncthreads();
        for (int o = FBB / 2; o > 0; o >>= 1) { if (tid < o) { sred[tid] += sred[tid + o]; sredi[tid] += sredi[tid + o]; } __syncthreads(); }
        sum = sred[0]; cnt = sredi[0]; __syncthreads();
        if (cnt == prev || cnt == 0) break;
        tau = (sum - 1.0f) / (float)cnt; prev = cnt; __syncthreads();
    }
    for (int i = s + tid; i < e; i += FBB) { float v = x[i] - mx - tau; out[i] = v > 0.0f ? v : 0.0f; }
}
__global__ void fb_sentinel(float* out) { if (threadIdx.x == 0 && blockIdx.x == 0) out[0] = 20000.0f; }

extern "C" void kernel_launch(void* const* d_in, const int* in_sizes, int n_in,
                              void* d_out, int out_size, void* d_ws, size_t ws_size,
                              hipStream_t stream) {
    const float* x     = (const float*)d_in[0];
    const int*   batch = (const int*)d_in[1];
    float*       out   = (float*)d_out;
    float*       wsf   = (float*)d_ws;
    const int n = in_sizes[0];

    // shared prefix: starts 8448(int) + mx 8192 + L1 + L2 + L3 + C1
    const size_t base_f  = (size_t)8448 + 8192 + L1N + L2N + L3N + L1N;
    const size_t small_f = base_f + 8192 + 8192;          // + baseA + rowP
    const size_t big_f   = small_f + (size_t)NTOT;        // + S
    if (n != NTOT || ws_size < small_f * sizeof(float)) {
        fb_sparsemax<<<NSEG, FBB, 0, stream>>>(x, batch, out, n);
        fb_sentinel<<<1, 64, 0, stream>>>(out);
        return;
    }
    int*   starts = (int*)wsf;
    float* mx     = wsf + 8448;
    float* L1 = mx + 8192;
    float* L2 = L1 + L1N;
    float* L3 = L2 + L2N;
    float* C1 = L3 + L3N;
    float* baseA = C1 + L1N;
    float* rowP  = baseA + 8192;

    const bool big = (ws_size >= big_f * sizeof(float));
    float* S = big ? (rowP + 8192) : out;   // big: S in ws (no S/out aliasing)

    k1_bounds<<<(n / 4 + 255) / 256, 256, 0, stream>>>(batch, starts, n);
    k2w<<<NSEG / 4, 256, 0, stream>>>(x, starts, mx, S, L1);
    kM1<<<128, 256, 0, stream>>>(S, starts, L1, L2, L3);
    kB<<<128, 256, 0, stream>>>(L1, L2, L3, C1);
    if (big) {
        kCF<<<NSEG / 4, 256, 0, stream>>>(x, S, C1, starts, batch, mx, out);
    } else {
        k_base<<<NSEG / 256, 256, 0, stream>>>(S, C1, starts, baseA, rowP);
        kC<<<NSEG, 128, 0, stream>>>(x, S, C1, starts, batch, mx, baseA, rowP, out);
    }
}